// Round 9
// baseline (58.146 us; speedup 1.0000x reference)
//
#include <hip/hip_runtime.h>

// Local NCC loss on (2,1,160,160,160) f32, 5x5x5 box window, SAME zero pad.
// R9: f2-strip compute to kill the b128 bank-conflict tax (782 cyc/block-slab,
// identical in v3/v5/v6/v8; b64 lane-stride-2 reads measured clean in v2).
// Block 256 thr (4 waves) = 16 sc x 16 rows; tile 32W x 16H x 8D; grid 2000
// (XCD-chunked, dz fastest). LDS raw[2][2][20][44] staged UNSHIFTED: aligned
// ds_write_b128 staging (2 tasks/thread), reads 3 ds_read_b64 per (row,vol)
// at even offsets. zs[5][5] f2 phase accumulators (50 VGPRs, static indices),
// v8's verified phase/completion guards. Outer a-loop unroll(1) (spill guard).

#define DIM 160
#define SLAB (DIM * DIM)
#define VOL (DIM * DIM * DIM)
#define TD 8
#define TH 16
#define ROWS 20                   // staged H rows: 16 + 4 halo
#define RST 44                    // padded row stride (floats)
#define NBLK 2000
#define NPART (NBLK * 4)

typedef float f4 __attribute__((ext_vector_type(4), aligned(16)));
typedef float f2 __attribute__((ext_vector_type(2), aligned(8)));

__global__ __launch_bounds__(256, 2) void ncc_main(const float* __restrict__ real,
                                                   const float* __restrict__ fake,
                                                   float* __restrict__ partials) {
    __shared__ __align__(16) float raw[2][2][ROWS][RST];   // 14080 B

    const int tid = threadIdx.x;

    // XCD-chunked swizzle: chunk = bid&7 (8 x 250), dz fastest inside a chunk.
    const int bid = blockIdx.x;
    const int vid = (bid & 7) * 250 + (bid >> 3);
    const int dz  = vid % 20;
    const int t1  = vid / 20;          // 0..99
    const int bx  = t1 % 5;
    const int by  = (t1 / 5) % 10;
    const int nb  = t1 / 50;
    const int w0 = 32 * bx, h0 = TH * by, d0 = TD * dz;

    const float* baseI = real + (size_t)nb * VOL;
    const float* baseJ = fake + (size_t)nb * VOL;

    // compute mapping: sc 0..15 (2-wide W strip), sr 0..15 (output row)
    const int sc = tid & 15;
    const int sr = tid >> 4;
    const int co = sr * RST + 2 * sc + 2;   // x = 2sc+2 <-> w = w0+2sc-2

    // staging: 400 tasks = 2 vols x 20 rows x 10 quads; task0 always, task1 if tid<144
    int gof[2], lof[2];
    bool ok[2];
    const float* src[2];
#pragma unroll
    for (int k = 0; k < 2; ++k) {
        const int t   = tid + 256 * k;
        const int vv  = t / 200;
        const int rem = t - 200 * vv;
        const int row = rem / 10;
        const int q   = rem - 10 * row;
        const int hg  = h0 - 2 + row;
        const int wq  = w0 - 4 + 4 * q;
        ok[k]  = (t < 400) && ((unsigned)hg < DIM) && (wq >= 0) && (wq + 3 < DIM);
        gof[k] = hg * DIM + wq;
        lof[k] = (vv * ROWS + row) * RST + 4 * q;   // ALIGNED f4 slot
        src[k] = vv ? baseJ : baseI;
    }

    // zero LDS once (halo/pad slots never staged stay zero forever)
    {
        float* L = &raw[0][0][0][0];
        for (int i = tid; i < 880; i += 256) *(f4*)(L + 4 * i) = (f4){0.f, 0.f, 0.f, 0.f};
    }
    __syncthreads();

    // prologue: stage slab d0-2 into buf0 (d0==0 -> OOB, stays zero)
    if (d0 > 0) {
        const size_t so = (size_t)(d0 - 2) * SLAB;
        float* L = &raw[0][0][0][0];
#pragma unroll
        for (int k = 0; k < 2; ++k)
            if (ok[k]) *(f4*)(L + lof[k]) = *(const f4*)(src[k] + so + gof[k]);
    }
    __syncthreads();

    const f2 z2 = (f2){0.f, 0.f};
    const f4 zf = (f4){0.f, 0.f, 0.f, 0.f};
    f2 zs[5][5];                       // [phase][quantity], static indices only
#pragma unroll
    for (int p = 0; p < 5; ++p)
#pragma unroll
        for (int q = 0; q < 5; ++q) zs[p][q] = z2;

    f2 acc = z2;
    const float inv = 1.0f / 125.0f;
    int cur = 0;

#pragma unroll 1
    for (int a = 0; a < 3; ++a) {      // s = 5a+b, slabs 0..11
        const bool am0 = (a > 0);
#pragma unroll
        for (int b = 0; b < 5; ++b) {
            const bool compAct  = (a < 2) || (b < 2);   // s <= 11
            const bool stageAct = (a < 2) || (b == 0);  // s <= 10
            if (!compAct) continue;

            // ---- issue next-slab loads into registers (zeros if D-OOB) ----
            f4 v0 = zf, v1 = zf;
            if (stageAct) {
                const int dd1 = d0 - 1 + 5 * a + b;
                if ((unsigned)dd1 < DIM) {
                    const size_t so = (size_t)dd1 * SLAB;
                    if (ok[0]) v0 = *(const f4*)(src[0] + so + gof[0]);
                    if (ok[1]) v1 = *(const f4*)(src[1] + so + gof[1]);
                }
            }

            // ---- compute current slab: vertical 5-sums from 30 b64 reads ----
            const float* LB = &raw[cur][0][0][0];
            f2 A0 = z2, A1 = z2, A2v = z2, B0 = z2, B1 = z2, B2v = z2;
            f2 A20 = z2, A21 = z2, A22 = z2, B20 = z2, B21 = z2, B22 = z2;
            f2 P0 = z2, P1 = z2, P2 = z2;
#pragma unroll
            for (int t = 0; t < 5; ++t) {
                const float* rp = LB + co + t * RST;
                const f2 a0 = *(const f2*)(rp);
                const f2 a1 = *(const f2*)(rp + 2);
                const f2 a2 = *(const f2*)(rp + 4);
                const f2 b0 = *(const f2*)(rp + ROWS * RST);
                const f2 b1 = *(const f2*)(rp + ROWS * RST + 2);
                const f2 b2 = *(const f2*)(rp + ROWS * RST + 4);
                A0 += a0; A1 += a1; A2v += a2;
                B0 += b0; B1 += b1; B2v += b2;
                A20 += a0 * a0; A21 += a1 * a1; A22 += a2 * a2;
                B20 += b0 * b0; B21 += b1 * b1; B22 += b2 * b2;
                P0 += a0 * b0; P1 += a1 * b1; P2 += a2 * b2;
            }
            // horizontal sliding 5-window: 2 outputs from 6 vertical sums
#define HW2(r0, r1, r2) ((f2){((r0.x + r0.y) + (r1.x + r1.y)) + r2.x, \
                              ((r0.y + r1.x) + (r1.y + r2.x)) + r2.y})
            const f2 cs0 = HW2(A0, A1, A2v);
            const f2 cs1 = HW2(B0, B1, B2v);
            const f2 cs2 = HW2(A20, A21, A22);
            const f2 cs3 = HW2(B20, B21, B22);
            const f2 cs4 = HW2(P0, P1, P2);
#undef HW2

            // ---- add into active D-phases (guards uniform, indices static) ----
#pragma unroll
            for (int p = 0; p < 5; ++p) {
                const int kk  = (b - p + 5) % 5;   // compile-time
                const int bmk = b - kk;            // compile-time
                const bool doadd = (am0 || p <= b) &&
                                   (a == 0 || (a == 1 ? (bmk <= 2) : (bmk <= -3)));
                if (doadd) {
                    zs[p][0] += cs0; zs[p][1] += cs1; zs[p][2] += cs2;
                    zs[p][3] += cs3; zs[p][4] += cs4;
                }
            }

            // ---- completed output depth od = s-4 -> cc for 2 outputs ----
            const bool docomp = (a == 0) ? (b == 4) : ((a == 1) ? true : (b < 2));
            if (docomp) {
                const int pe = (b + 1) % 5;        // compile-time
                const f2 SI = zs[pe][0], SJ = zs[pe][1];
                const f2 S2I = zs[pe][2], S2J = zs[pe][3], SIJ = zs[pe][4];
                const f2 t0    = SI * inv;
                const f2 cross = SIJ - t0 * SJ;
                const f2 iv    = S2I - t0 * SI;
                const f2 jv    = S2J - (SJ * inv) * SJ;
                acc += cross * cross / (iv * jv + 1e-5f);
                zs[pe][0] = z2; zs[pe][1] = z2; zs[pe][2] = z2;
                zs[pe][3] = z2; zs[pe][4] = z2;
            }

            // ---- write staged regs into other buffer (zeros when D-OOB) ----
            if (stageAct) {
                float* LW = &raw[cur ^ 1][0][0][0];
                if (ok[0]) *(f4*)(LW + lof[0]) = v0;
                if (ok[1]) *(f4*)(LW + lof[1]) = v1;
            }
            __syncthreads();
            cur ^= 1;
        }
    }

    // ---- wave reduction -> one partial per wave ----
    float a2 = acc.x + acc.y;
#pragma unroll
    for (int off = 32; off; off >>= 1)
        a2 += __shfl_down(a2, off, 64);
    if ((tid & 63) == 0)
        partials[bid * 4 + (tid >> 6)] = a2;
}

__global__ void ncc_reduce(const float* __restrict__ partials, float* __restrict__ out) {
    __shared__ double ws[4];
    double s = 0.0;
    for (int i = threadIdx.x; i < NPART; i += 256) s += (double)partials[i];
#pragma unroll
    for (int off = 32; off; off >>= 1)
        s += __shfl_down(s, off, 64);
    if ((threadIdx.x & 63) == 0) ws[threadIdx.x >> 6] = s;
    __syncthreads();
    if (threadIdx.x == 0) {
        const double t = ws[0] + ws[1] + ws[2] + ws[3];
        out[0] = (float)(t / (2.0 * (double)VOL));
    }
}

extern "C" void kernel_launch(void* const* d_in, const int* in_sizes, int n_in,
                              void* d_out, int out_size, void* d_ws, size_t ws_size,
                              hipStream_t stream) {
    const float* real = (const float*)d_in[0];
    const float* fake = (const float*)d_in[1];
    float* out      = (float*)d_out;
    float* partials = (float*)d_ws;   // NPART floats

    ncc_main<<<dim3(NBLK), dim3(256), 0, stream>>>(real, fake, partials);
    ncc_reduce<<<1, 256, 0, stream>>>(partials, out);
}

// Round 10
// 55.905 us; speedup vs baseline: 1.0401x; 1.0401x over previous
//
#include <hip/hip_runtime.h>

// Local NCC loss on (2,1,160,160,160) f32, 5x5x5 box window, SAME zero pad.
// R10 = v8 tile/structure + v9 clean LDS access + 2Hx2W outputs/thread.
// Block 256 thr (4 waves) = 16 sc x 16 sr; tile 32W x 32H x 8D; grid 1000
// (XCD-chunked, dz fastest). LDS raw[2][2][36][44] staged with ALIGNED f4
// writes (3 tasks/thread, v9-verified clean); reads 3 ds_read_b64 per
// (row,vol) at stride-2-over-16-lanes (v9-verified clean), 6 rows covering
// both H windows. W-window applied per row BEFORE vertical sums (H/W sums
// commute) so vertical state = 20 floats; phase state zr[2][5][5] f2 = 100
// floats (v8-verified guards). Outer a-loop unroll(1) (spill guard).

#define DIM 160
#define SLAB (DIM * DIM)
#define VOL (DIM * DIM * DIM)
#define TD 8
#define ROWS 36                   // staged H rows: 32 + 4 halo
#define RST 44                    // padded row stride (floats)
#define VOFF (ROWS * RST)         // J-volume offset inside a buffer
#define NBLK 1000
#define NPART (NBLK * 4)

typedef float f4 __attribute__((ext_vector_type(4), aligned(16)));
typedef float f2 __attribute__((ext_vector_type(2), aligned(8)));

// sliding 5-window sums for 2 outputs from 3 f2 (6 consecutive values)
__device__ __forceinline__ f2 hw2(const f2 r0, const f2 r1, const f2 r2) {
    const float c = (r0.y + r1.x) + r1.y;
    return (f2){(r0.x + c) + r2.x, (c + r2.x) + r2.y};
}

__global__ __launch_bounds__(256, 2) void ncc_main(const float* __restrict__ real,
                                                   const float* __restrict__ fake,
                                                   float* __restrict__ partials) {
    __shared__ __align__(16) float raw[2][2][ROWS][RST];   // 25344 B

    const int tid = threadIdx.x;

    // XCD-chunked swizzle: chunk = bid&7 (8 chunks of 125), dz fastest inside.
    const int bid = blockIdx.x;
    const int vid = (bid & 7) * 125 + (bid >> 3);
    const int dz  = vid % 20;
    const int t1  = vid / 20;      // 0..49
    const int bx  = t1 % 5;
    const int by  = (t1 / 5) % 5;
    const int nb  = t1 / 25;
    const int w0 = 32 * bx, h0 = 32 * by, d0 = TD * dz;

    const float* baseI = real + (size_t)nb * VOL;
    const float* baseJ = fake + (size_t)nb * VOL;

    // compute mapping: sc 0..15 (2-wide W strip), sr 0..15 (rows 2sr, 2sr+1)
    const int sc = tid & 15;
    const int sr = tid >> 4;
    const int co = (2 * sr) * RST + 2 * sc + 2;   // x = 2sc+2 <-> w = w0+2sc-2

    // staging: 720 tasks = 2 vols x 36 rows x 10 quads; 3 per thread
    int gof[3], lof[3];
    bool ok[3];
    const float* src[3];
#pragma unroll
    for (int k = 0; k < 3; ++k) {
        const int t   = tid + 256 * k;
        const int tv  = t / 360;
        const int rem = t - 360 * tv;
        const int row = rem / 10;
        const int q   = rem - 10 * row;
        const int hg  = h0 - 2 + row;
        const int wq  = w0 - 4 + 4 * q;
        ok[k]  = (t < 720) && ((unsigned)hg < DIM) && (wq >= 0) && (wq + 3 < DIM);
        gof[k] = hg * DIM + wq;
        lof[k] = (tv * ROWS + row) * RST + 4 * q;   // ALIGNED f4 slot
        src[k] = tv ? baseJ : baseI;
    }

    // zero LDS once (never-staged halo/pad slots stay zero forever)
    {
        float* L = &raw[0][0][0][0];
        for (int i = tid; i < 2 * 2 * ROWS * RST / 4; i += 256)
            *(f4*)(L + 4 * i) = (f4){0.f, 0.f, 0.f, 0.f};
    }
    __syncthreads();

    // prologue: stage slab d0-2 into buf0 (d0==0 -> OOB, stays zero)
    if (d0 > 0) {
        const size_t so = (size_t)(d0 - 2) * SLAB;
        float* L = &raw[0][0][0][0];
#pragma unroll
        for (int k = 0; k < 3; ++k)
            if (ok[k]) *(f4*)(L + lof[k]) = *(const f4*)(src[k] + so + gof[k]);
    }
    __syncthreads();

    const f2 z2 = (f2){0.f, 0.f};
    const f4 zf = (f4){0.f, 0.f, 0.f, 0.f};
    f2 zr0[5][5], zr1[5][5];           // [phase][quantity] per H row, static only
#pragma unroll
    for (int p = 0; p < 5; ++p)
#pragma unroll
        for (int q = 0; q < 5; ++q) { zr0[p][q] = z2; zr1[p][q] = z2; }

    f2 acc = z2;
    const float inv = 1.0f / 125.0f;
    int cur = 0;

#pragma unroll 1
    for (int a = 0; a < 3; ++a) {      // s = 5a+b, slabs 0..11
        const bool am0 = (a > 0);
#pragma unroll
        for (int b = 0; b < 5; ++b) {
            const bool compAct  = (a < 2) || (b < 2);   // s <= 11
            const bool stageAct = (a < 2) || (b == 0);  // s <= 10
            if (!compAct) continue;

            // ---- issue next-slab loads into registers (zeros if D-OOB) ----
            f4 v0 = zf, v1 = zf, v2 = zf;
            if (stageAct) {
                const int dd1 = d0 - 1 + 5 * a + b;
                if ((unsigned)dd1 < DIM) {
                    const size_t so = (size_t)dd1 * SLAB;
                    if (ok[0]) v0 = *(const f4*)(src[0] + so + gof[0]);
                    if (ok[1]) v1 = *(const f4*)(src[1] + so + gof[1]);
                    if (ok[2]) v2 = *(const f4*)(src[2] + so + gof[2]);
                }
            }

            // ---- compute current slab: per-row W windows, 2 vertical sums ----
            const float* LB = &raw[cur][0][0][0];
            f2 c00 = z2, c01 = z2, c02 = z2, c03 = z2, c04 = z2;   // row 2sr
            f2 c10 = z2, c11 = z2, c12 = z2, c13 = z2, c14 = z2;   // row 2sr+1
#pragma unroll
            for (int t = 0; t < 6; ++t) {
                const float* rp = LB + co + t * RST;
                const f2 a0 = *(const f2*)(rp);
                const f2 a1 = *(const f2*)(rp + 2);
                const f2 a2 = *(const f2*)(rp + 4);
                const f2 b0 = *(const f2*)(rp + VOFF);
                const f2 b1 = *(const f2*)(rp + VOFF + 2);
                const f2 b2 = *(const f2*)(rp + VOFF + 4);
                const f2 w0v = hw2(a0, a1, a2);
                const f2 w1v = hw2(b0, b1, b2);
                const f2 w2v = hw2(a0 * a0, a1 * a1, a2 * a2);
                const f2 w3v = hw2(b0 * b0, b1 * b1, b2 * b2);
                const f2 w4v = hw2(a0 * b0, a1 * b1, a2 * b2);
                if (t < 5) { c00 += w0v; c01 += w1v; c02 += w2v; c03 += w3v; c04 += w4v; }
                if (t > 0) { c10 += w0v; c11 += w1v; c12 += w2v; c13 += w3v; c14 += w4v; }
            }

            // ---- add into active D-phases (guards uniform, indices static) ----
#pragma unroll
            for (int p = 0; p < 5; ++p) {
                const int kk  = (b - p + 5) % 5;   // compile-time
                const int bmk = b - kk;            // compile-time
                const bool doadd = (am0 || p <= b) &&
                                   (a == 0 || (a == 1 ? (bmk <= 2) : (bmk <= -3)));
                if (doadd) {
                    zr0[p][0] += c00; zr0[p][1] += c01; zr0[p][2] += c02;
                    zr0[p][3] += c03; zr0[p][4] += c04;
                    zr1[p][0] += c10; zr1[p][1] += c11; zr1[p][2] += c12;
                    zr1[p][3] += c13; zr1[p][4] += c14;
                }
            }

            // ---- completed output depth od = s-4 -> cc for 2x2 outputs ----
            const bool docomp = (a == 0) ? (b == 4) : ((a == 1) ? true : (b < 2));
            if (docomp) {
                const int pe = (b + 1) % 5;        // compile-time
                {
                    const f2 SI = zr0[pe][0], SJ = zr0[pe][1];
                    const f2 S2I = zr0[pe][2], S2J = zr0[pe][3], SIJ = zr0[pe][4];
                    const f2 t0    = SI * inv;
                    const f2 cross = SIJ - t0 * SJ;
                    const f2 iv    = S2I - t0 * SI;
                    const f2 jv    = S2J - (SJ * inv) * SJ;
                    acc += cross * cross / (iv * jv + 1e-5f);
                    zr0[pe][0] = z2; zr0[pe][1] = z2; zr0[pe][2] = z2;
                    zr0[pe][3] = z2; zr0[pe][4] = z2;
                }
                {
                    const f2 SI = zr1[pe][0], SJ = zr1[pe][1];
                    const f2 S2I = zr1[pe][2], S2J = zr1[pe][3], SIJ = zr1[pe][4];
                    const f2 t0    = SI * inv;
                    const f2 cross = SIJ - t0 * SJ;
                    const f2 iv    = S2I - t0 * SI;
                    const f2 jv    = S2J - (SJ * inv) * SJ;
                    acc += cross * cross / (iv * jv + 1e-5f);
                    zr1[pe][0] = z2; zr1[pe][1] = z2; zr1[pe][2] = z2;
                    zr1[pe][3] = z2; zr1[pe][4] = z2;
                }
            }

            // ---- write staged regs into other buffer (zeros when D-OOB) ----
            if (stageAct) {
                float* LW = &raw[cur ^ 1][0][0][0];
                if (ok[0]) *(f4*)(LW + lof[0]) = v0;
                if (ok[1]) *(f4*)(LW + lof[1]) = v1;
                if (ok[2]) *(f4*)(LW + lof[2]) = v2;
            }
            __syncthreads();
            cur ^= 1;
        }
    }

    // ---- wave reduction -> one partial per wave ----
    float a2 = acc.x + acc.y;
#pragma unroll
    for (int off = 32; off; off >>= 1)
        a2 += __shfl_down(a2, off, 64);
    if ((tid & 63) == 0)
        partials[bid * 4 + (tid >> 6)] = a2;
}

__global__ void ncc_reduce(const float* __restrict__ partials, float* __restrict__ out) {
    __shared__ double ws[4];
    double s = 0.0;
    for (int i = threadIdx.x; i < NPART; i += 256) s += (double)partials[i];
#pragma unroll
    for (int off = 32; off; off >>= 1)
        s += __shfl_down(s, off, 64);
    if ((threadIdx.x & 63) == 0) ws[threadIdx.x >> 6] = s;
    __syncthreads();
    if (threadIdx.x == 0) {
        const double t = ws[0] + ws[1] + ws[2] + ws[3];
        out[0] = (float)(t / (2.0 * (double)VOL));
    }
}

extern "C" void kernel_launch(void* const* d_in, const int* in_sizes, int n_in,
                              void* d_out, int out_size, void* d_ws, size_t ws_size,
                              hipStream_t stream) {
    const float* real = (const float*)d_in[0];
    const float* fake = (const float*)d_in[1];
    float* out      = (float*)d_out;
    float* partials = (float*)d_ws;   // NPART floats

    ncc_main<<<dim3(NBLK), dim3(256), 0, stream>>>(real, fake, partials);
    ncc_reduce<<<1, 256, 0, stream>>>(partials, out);
}